// Round 9
// baseline (355.675 us; speedup 1.0000x reference)
//
#include <hip/hip_runtime.h>
#include <hip/hip_bf16.h>

constexpr int N_NODES = 20000;
constexpr int N_EDGES = 50000;
constexpr int IN_DIM  = 512;
constexpr int D       = 32;

typedef float vf4 __attribute__((ext_vector_type(4)));

// ws layout (floats): deg int[20480] | sumc f[20480] | Bacc f[640000] | A f[640000]
constexpr size_t OFF_DEG  = 0;
constexpr size_t OFF_SUMC = 20480;
constexpr size_t OFF_BACC = 40960;
constexpr size_t OFF_A    = 680960;

__device__ __forceinline__ float dot4(vf4 a, vf4 b) {
    return fmaf(a.x, b.x, fmaf(a.y, b.y, fmaf(a.z, b.z, a.w * b.w)));
}

// ---------------------------------------------------------------------------
// MEASUREMENT PROBE: pure read-stream of T0+T1 (819 MB), best-case pattern.
// Sink -> Bacc region (re-zeroed by the following memset, so pipeline is
// unaffected; compiler cannot DCE the loads).
__global__ __launch_bounds__(256) void k_probe(const float* __restrict__ TA,
                                               const float* __restrict__ TB,
                                               float* __restrict__ sink) {
    const int gtid = blockIdx.x * 256 + threadIdx.x;
    const int nth  = gridDim.x * 256;
    const size_t nv = (size_t)2 * N_EDGES * D * D / 4;   // vf4 count per tensor
    const vf4* a = (const vf4*)TA;
    const vf4* b = (const vf4*)TB;
    float acc = 0.0f;
    for (size_t i = gtid; i < nv; i += nth) {
        vf4 v = a[i];
        vf4 w = b[i];
        acc += v.x + v.y + v.z + v.w + w.x + w.y + w.z + w.w;
    }
    sink[gtid % 524288] = acc;
}

// ---------------------------------------------------------------------------
// h = relu(x @ W + b) -> A ; fused integer degree histogram (40 slots/block)
__global__ __launch_bounds__(256) void k_proj(const float* __restrict__ x,
                                              const float* __restrict__ W,
                                              const float* __restrict__ b,
                                              const int* __restrict__ ei,
                                              float* __restrict__ A,
                                              int* __restrict__ deg) {
    __shared__ float xs[8][IN_DIM];
    const int tid  = threadIdx.x;
    const int row0 = blockIdx.x * 8;

    if (tid < 40) atomicAdd(&deg[ei[blockIdx.x * 40 + tid]], 1);

    const vf4* xsrc = (const vf4*)(x + (size_t)row0 * IN_DIM);
    vf4* xdst = (vf4*)&xs[0][0];
    #pragma unroll
    for (int i = 0; i < 4; ++i) xdst[tid + 256 * i] = xsrc[tid + 256 * i];
    __syncthreads();

    const int r = tid >> 5;
    const int c = tid & 31;
    const float* xr = xs[r];
    float acc = b[c];
    #pragma unroll 4
    for (int k = 0; k < IN_DIM; k += 4) {
        acc = fmaf(xr[k + 0], W[(k + 0) * D + c], acc);
        acc = fmaf(xr[k + 1], W[(k + 1) * D + c], acc);
        acc = fmaf(xr[k + 2], W[(k + 2) * D + c], acc);
        acc = fmaf(xr[k + 3], W[(k + 3) * D + c], acc);
    }
    A[(size_t)(row0 + r) * D + c] = fmaxf(acc, 0.0f);
}

// ---------------------------------------------------------------------------
// One wave per TWO transports (R2-proven body). Atomic scatter into Bacc/sumc.
__global__ __launch_bounds__(256) void k_edge(const float* __restrict__ T,
                                              const float* __restrict__ rw,
                                              const float* __restrict__ alpha_p,
                                              const int* __restrict__ src,
                                              const int* __restrict__ dst,
                                              const int* __restrict__ deg,
                                              const float* __restrict__ hA,
                                              float* __restrict__ Bacc,
                                              float* __restrict__ sumc) {
    const int wave = (blockIdx.x * 256 + threadIdx.x) >> 6;
    const int lane = threadIdx.x & 63;
    const int t0 = wave * 2;
    const int t1 = t0 + 1;

    int in0, out0, in1, out1;
    {
        int e0 = (t0 < N_EDGES) ? t0 : t0 - N_EDGES;
        if (t0 < N_EDGES) { in0 = src[e0]; out0 = dst[e0]; }
        else              { in0 = dst[e0]; out0 = src[e0]; }
        int e1 = (t1 < N_EDGES) ? t1 : t1 - N_EDGES;
        if (t1 < N_EDGES) { in1 = src[e1]; out1 = dst[e1]; }
        else              { in1 = dst[e1]; out1 = src[e1]; }
    }

    const int g = lane >> 3;   // row-group 0..7
    const int m = lane & 7;    // k-chunk  0..7

    const vf4* T0p = (const vf4*)(T + (size_t)t0 * (D * D));   // t1 follows contiguously
    vf4 a00 = T0p[lane],       a01 = T0p[64 + lane],  a02 = T0p[128 + lane], a03 = T0p[192 + lane];
    vf4 a10 = T0p[256 + lane], a11 = T0p[320 + lane], a12 = T0p[384 + lane], a13 = T0p[448 + lane];
    vf4 h0 = ((const vf4*)(hA + (size_t)in0 * D))[m];
    vf4 h1 = ((const vf4*)(hA + (size_t)in1 * D))[m];

    const float alpha = alpha_p[0];
    const float c0 = alpha * log1pf(expf(rw[t0])) / fmaxf((float)deg[out0], 1.0f);
    const float c1 = alpha * log1pf(expf(rw[t1])) / fmaxf((float)deg[out1], 1.0f);

    float p00 = dot4(a00, h0), p01 = dot4(a01, h0), p02 = dot4(a02, h0), p03 = dot4(a03, h0);
    float p10 = dot4(a10, h1), p11 = dot4(a11, h1), p12 = dot4(a12, h1), p13 = dot4(a13, h1);

    #define RED8(p) { p += __shfl_xor(p, 1); p += __shfl_xor(p, 2); p += __shfl_xor(p, 4); }
    RED8(p00) RED8(p01) RED8(p02) RED8(p03)
    RED8(p10) RED8(p11) RED8(p12) RED8(p13)
    #undef RED8

    if (m < 4) {
        const float v0 = (m == 0) ? p00 : (m == 1) ? p01 : (m == 2) ? p02 : p03;
        const float v1 = (m == 0) ? p10 : (m == 1) ? p11 : (m == 2) ? p12 : p13;
        const int row = m * 8 + g;
        atomicAdd(&Bacc[(size_t)out0 * D + row], c0 * v0);
        atomicAdd(&Bacc[(size_t)out1 * D + row], c1 * v1);
    }
    if (lane == 0)  atomicAdd(&sumc[out0], c0);
    if (lane == 32) atomicAdd(&sumc[out1], c1);
}

// ---------------------------------------------------------------------------
// h_pre = h*(1-sumc) + Bacc ; y = relu(layernorm(h_pre)) -> dest
__global__ __launch_bounds__(256) void k_ln(const float* __restrict__ h,
                                            float* __restrict__ Bacc,
                                            float* __restrict__ sumc,
                                            const float* __restrict__ gam,
                                            const float* __restrict__ bet,
                                            float* __restrict__ dest,
                                            int do_zero) {
    const int tid = threadIdx.x;
    const int row = blockIdx.x * 8 + (tid >> 5);
    const int c   = tid & 31;
    const size_t idx = (size_t)row * D + c;

    const float sc = sumc[row];
    const float v  = h[idx] * (1.0f - sc) + Bacc[idx];

    float s = v;
    #pragma unroll
    for (int msk = 16; msk >= 1; msk >>= 1) s += __shfl_xor(s, msk);
    const float mu = s * (1.0f / 32.0f);
    const float dv = v - mu;
    float q = dv * dv;
    #pragma unroll
    for (int msk = 16; msk >= 1; msk >>= 1) q += __shfl_xor(q, msk);
    const float var = q * (1.0f / 32.0f);

    float y = dv * rsqrtf(var + 1e-5f) * gam[c] + bet[c];
    dest[idx] = fmaxf(y, 0.0f);

    if (do_zero) {
        Bacc[idx] = 0.0f;
        if (c == 0) sumc[row] = 0.0f;
    }
}

// ---------------------------------------------------------------------------
extern "C" void kernel_launch(void* const* d_in, const int* in_sizes, int n_in,
                              void* d_out, int out_size, void* d_ws, size_t ws_size,
                              hipStream_t stream) {
    const float* x      = (const float*)d_in[0];
    const int*   ei     = (const int*)  d_in[1];   // [2, E]: src row | dst row
    const float* W      = (const float*)d_in[2];
    const float* b      = (const float*)d_in[3];
    const float* alpha0 = (const float*)d_in[4];
    const float* T0     = (const float*)d_in[5];
    const float* rw0    = (const float*)d_in[6];
    const float* g0     = (const float*)d_in[7];
    const float* be0    = (const float*)d_in[8];
    const float* alpha1 = (const float*)d_in[9];
    const float* T1     = (const float*)d_in[10];
    const float* rw1    = (const float*)d_in[11];
    const float* g1     = (const float*)d_in[12];
    const float* be1    = (const float*)d_in[13];

    float* out = (float*)d_out;
    int*   wsi = (int*)d_ws;
    float* wsf = (float*)d_ws;

    int*   deg  = wsi + OFF_DEG;
    float* sumc = wsf + OFF_SUMC;
    float* Bacc = wsf + OFF_BACC;
    float* A    = wsf + OFF_A;

    const int* src = ei;
    const int* dst = ei + N_EDGES;

    // --- measurement probe: pure stream of T0+T1 (819 MB). Sink into Bacc,
    //     which the memset below re-zeroes, so the pipeline is unaffected.
    k_probe<<<2048, 256, 0, stream>>>(T0, T1, Bacc);

    // zero deg + sumc + Bacc in one memset
    (void)hipMemsetAsync(wsi, 0, OFF_A * sizeof(float), stream);

    k_proj<<<N_NODES / 8, 256, 0, stream>>>(x, W, b, ei, A, deg);

    const int edge_blocks = (2 * N_EDGES) / 8;   // 2 transports/wave, 4 waves/block
    k_edge<<<edge_blocks, 256, 0, stream>>>(T0, rw0, alpha0, src, dst, deg, A, Bacc, sumc);
    k_ln<<<N_NODES / 8, 256, 0, stream>>>(A, Bacc, sumc, g0, be0, A, 1);

    k_edge<<<edge_blocks, 256, 0, stream>>>(T1, rw1, alpha1, src, dst, deg, A, Bacc, sumc);
    k_ln<<<N_NODES / 8, 256, 0, stream>>>(A, Bacc, sumc, g1, be1, out, 0);
}